// Round 12
// baseline (536.424 us; speedup 1.0000x reference)
//
#include <hip/hip_runtime.h>

#define SLEN  2048
#define BATCH 4096
#define HBAT  2048   // stream B batch offset

// DPP cross-lane move (VALU-speed, no LDS/lgkm).
template<int CTRL>
__device__ __forceinline__ float dppf(float v) {
    return __int_as_float(
        __builtin_amdgcn_update_dpp(0, __float_as_int(v), CTRL, 0xF, 0xF, true));
}
#define DPP_XOR1 0xB1   // quad_perm [1,0,3,2]
#define DPP_XOR2 0x4E   // quad_perm [2,3,0,1]
#define DPP_XOR3 0x1B   // quad_perm [3,2,1,0]
#define DPP_XOR7 0x141  // ROW_HALF_MIRROR (i ^ 7 within 8)

// dst = bcast(x2[Q]) * w + b   (op_sel dword-broadcast from a pair; fresh dest)
template<int Q>
__device__ __forceinline__ float2 pkfma_init(float2 x2, float2 w, float2 b) {
    float2 dst;
    if constexpr (Q == 0)
        asm("v_pk_fma_f32 %0, %1, %2, %3 op_sel:[0,0,0] op_sel_hi:[0,1,1]"
            : "=v"(dst) : "v"(x2), "v"(w), "v"(b));
    else
        asm("v_pk_fma_f32 %0, %1, %2, %3 op_sel:[1,0,0] op_sel_hi:[1,1,1]"
            : "=v"(dst) : "v"(x2), "v"(w), "v"(b));
    return dst;
}
// acc += bcast(h2[Q]) * w  (op_sel dword-broadcast; tied accumulator)
template<int Q>
__device__ __forceinline__ void pkfma_bc(float2& acc, float2 h2, float2 w) {
    if constexpr (Q == 0)
        asm("v_pk_fma_f32 %0, %1, %2, %0 op_sel:[0,0,0] op_sel_hi:[0,1,1]"
            : "+v"(acc) : "v"(h2), "v"(w));
    else
        asm("v_pk_fma_f32 %0, %1, %2, %0 op_sel:[1,0,0] op_sel_hi:[1,1,1]"
            : "+v"(acc) : "v"(h2), "v"(w));
}

extern "C" __global__ __launch_bounds__(256, 1)
void bilstm_kernel(const float* __restrict__ x,
                   const float* __restrict__ w_ih_f, const float* __restrict__ w_hh_f,
                   const float* __restrict__ b_ih_f, const float* __restrict__ b_hh_f,
                   const float* __restrict__ w_ih_b, const float* __restrict__ w_hh_b,
                   const float* __restrict__ b_ih_b, const float* __restrict__ b_hh_b,
                   const float* __restrict__ w_out, const float* __restrict__ b_out,
                   const int* __restrict__ future_p,
                   float* __restrict__ out)
{
    const int tid  = threadIdx.x;
    const int wv   = tid >> 6;     // wave in block (0..3)
    const int lane = tid & 63;
    const int e    = lane >> 4;    // batch elem within wave (0..3)
    const int r    = lane & 15;
    const int d    = r >> 3;       // 0 = fwd, 1 = bwd
    const int j    = r & 7;        // hidden index
    const int bA   = blockIdx.x * 16 + wv * 4 + e;   // stream A elem; B = bA + HBAT

    const float* wih_p = d ? w_ih_b : w_ih_f;
    const float* whh_p = d ? w_hh_b : w_hh_f;
    const float* bih_p = d ? b_ih_b : b_ih_f;
    const float* bhh_p = d ? b_hh_b : b_hh_f;

    // Prescale so gate accumulators emerge as exp2 arguments (R7-proven):
    //   sigmoid(v) = 1/(1+exp2(-log2e*v)),  tanh(v) = 2/(1+exp2(-2log2e*v)) - 1
    const float SI = -1.4426950408889634f;   // i, f, o rows
    const float SG = -2.8853900817779268f;   // g row

    // Butterfly slot -> h index xor mask (pairs: lo,hi of P0..P3)
    const int M[8] = {0, 1, 2, 3, 7, 6, 5, 4};
    float2 Wif[8], Wgo[8], wih_if, wih_go, b_if, b_go;
    #pragma unroll
    for (int m = 0; m < 8; ++m) {
        const int idx = j ^ M[m];
        Wif[m].x = SI * whh_p[(0 + j) * 8 + idx];     // gate i
        Wif[m].y = SI * whh_p[(8 + j) * 8 + idx];     // gate f
        Wgo[m].x = SG * whh_p[(16 + j) * 8 + idx];    // gate g
        Wgo[m].y = SI * whh_p[(24 + j) * 8 + idx];    // gate o
    }
    wih_if.x = SI * wih_p[0 + j];   wih_if.y = SI * wih_p[8 + j];
    wih_go.x = SG * wih_p[16 + j];  wih_go.y = SI * wih_p[24 + j];
    b_if.x = SI * (bih_p[0 + j]  + bhh_p[0 + j]);
    b_if.y = SI * (bih_p[8 + j]  + bhh_p[8 + j]);
    b_go.x = SG * (bih_p[16 + j] + bhh_p[16 + j]);
    b_go.y = SI * (bih_p[24 + j] + bhh_p[24 + j]);

    const float wout = w_out[d * 8 + j];
    const float bout = b_out[0];
    const int   fut  = future_p[0];

    // Per stream: [wave][row = e*2+d][72]: slots 0..31 = outputs (j==0 lane),
    // 32+j+slot = dump region for non-writer lanes (never read).
    __shared__ float o_lds[2][4][8][72];
    float* o_ptrA  = &o_lds[0][wv][e * 2 + d][(j == 0) ? 0 : (32 + j)];
    float* o_ptrB  = &o_lds[1][wv][e * 2 + d][(j == 0) ? 0 : (32 + j)];
    float* o_baseA = &o_lds[0][wv][0][0];
    float* o_baseB = &o_lds[1][wv][0][0];

    float cA = 0.0f, hnA = 0.0f;
    float cB = 0.0f, hnB = 0.0f;

    // x addressing: byte-voffsets walk rows; x spans 2^25 bytes so the bwd
    // mod-S wrap is a simple mask. Stream B shares voffs with a +8192 B base
    // (bB = bA + 2048: same row, column bA+2048 < 4096 — always in-bounds).
    const char* xpA = (const char*)x;
    const char* xpB = (const char*)x + HBAT * 4;
    const unsigned vdelta  = d ? (unsigned)(-(BATCH * 4)) : (unsigned)(BATCH * 4);
    const unsigned vd8     = vdelta * 8u;
    const unsigned vmask   = (unsigned)(SLEN * BATCH * 4 - 1);
    unsigned voffs[8];
    {
        unsigned v0 = ((unsigned)(d ? (fut & (SLEN - 1)) : 0) * BATCH + (unsigned)bA) * 4u;
        #pragma unroll
        for (int u = 0; u < 8; ++u) { voffs[u] = v0; v0 = (v0 + vdelta) & vmask; }
    }

    // x pairs per stream: bank[p] holds steps (2p, 2p+1) of an 8-step block
    float2 xaA[4], xqA[4], xaB[4], xqB[4];
    #pragma unroll
    for (int p = 0; p < 4; ++p) {
        xaA[p].x = *(const float*)(xpA + voffs[2 * p]);
        xaA[p].y = *(const float*)(xpA + voffs[2 * p + 1]);
        xaB[p].x = *(const float*)(xpB + voffs[2 * p]);
        xaB[p].y = *(const float*)(xpB + voffs[2 * p + 1]);
    }
    #pragma unroll
    for (int u = 0; u < 8; ++u) voffs[u] = (voffs[u] + vd8) & vmask;

    // One LSTM step for one stream; acc_* pre-initialized with x*w_ih + bias.
    // Activation block is R7's exact scalar numerics (5 exp2, 3 rcp).
    auto STEP = [&](float& c, float& hn, float* o_ptr,
                    float2 acc_if, float2 acc_go, int slot) {
        // all-gather h across the 8 j-lanes of this (e,d): 7 DPP movs
        float2 P0, P1, P2, P3;
        P0.x = hn;                      // h[j]
        P0.y = dppf<DPP_XOR1>(hn);      // h[j^1]
        P1.x = dppf<DPP_XOR2>(hn);      // h[j^2]
        P1.y = dppf<DPP_XOR3>(hn);      // h[j^3]
        P2.x = dppf<DPP_XOR7>(P0.x);    // h[j^7]
        P2.y = dppf<DPP_XOR7>(P0.y);    // h[j^6]
        P3.x = dppf<DPP_XOR7>(P1.x);    // h[j^5]
        P3.y = dppf<DPP_XOR7>(P1.y);    // h[j^4]

        pkfma_bc<0>(acc_if, P0, Wif[0]);  pkfma_bc<1>(acc_if, P0, Wif[1]);
        pkfma_bc<0>(acc_if, P1, Wif[2]);  pkfma_bc<1>(acc_if, P1, Wif[3]);
        pkfma_bc<0>(acc_if, P2, Wif[4]);  pkfma_bc<1>(acc_if, P2, Wif[5]);
        pkfma_bc<0>(acc_if, P3, Wif[6]);  pkfma_bc<1>(acc_if, P3, Wif[7]);
        pkfma_bc<0>(acc_go, P0, Wgo[0]);  pkfma_bc<1>(acc_go, P0, Wgo[1]);
        pkfma_bc<0>(acc_go, P1, Wgo[2]);  pkfma_bc<1>(acc_go, P1, Wgo[3]);
        pkfma_bc<0>(acc_go, P2, Wgo[4]);  pkfma_bc<1>(acc_go, P2, Wgo[5]);
        pkfma_bc<0>(acc_go, P3, Wgo[6]);  pkfma_bc<1>(acc_go, P3, Wgo[7]);

        // R7-exact activations: merged rcps (2) + tanh rcp (1)
        float ei = __builtin_amdgcn_exp2f(acc_if.x);
        float ef = __builtin_amdgcn_exp2f(acc_if.y);
        float eg = __builtin_amdgcn_exp2f(acc_go.x);
        float eo = __builtin_amdgcn_exp2f(acc_go.y);
        float ei1 = 1.0f + ei, ef1 = 1.0f + ef, eg1 = 1.0f + eg, eo1 = 1.0f + eo;
        float riu = __builtin_amdgcn_rcpf(ei1 * eg1);
        float ig  = (2.0f - eg1) * riu;          // = ia*ga
        float rv  = __builtin_amdgcn_rcpf(ef1 * eo1);
        float fa  = rv * eo1;
        float oa  = rv * ef1;
        c = fmaf(fa, c, ig);
        float tc = __builtin_amdgcn_exp2f(SG * c);
        float rt = __builtin_amdgcn_rcpf(1.0f + tc);
        float T  = fmaf(2.0f, rt, -1.0f);        // tanh(c)
        hn = oa * T;

        // per-(e,d) output partial: reduce over the 8 j-lanes, dump-write
        float p = hn * wout;
        p += dppf<DPP_XOR1>(p);
        p += dppf<DPP_XOR2>(p);
        p += dppf<DPP_XOR7>(p);
        o_ptr[slot] = p;
    };

    for (int T = 0; T < SLEN; T += 32) {
        #pragma unroll
        for (int blk = 0; blk < 4; ++blk) {
            // prefetch next 8 x values (both streams) into the other bank
            #pragma unroll
            for (int p = 0; p < 4; ++p) {
                if (blk & 1) {
                    xaA[p].x = *(const float*)(xpA + voffs[2 * p]);
                    xaA[p].y = *(const float*)(xpA + voffs[2 * p + 1]);
                    xaB[p].x = *(const float*)(xpB + voffs[2 * p]);
                    xaB[p].y = *(const float*)(xpB + voffs[2 * p + 1]);
                } else {
                    xqA[p].x = *(const float*)(xpA + voffs[2 * p]);
                    xqA[p].y = *(const float*)(xpA + voffs[2 * p + 1]);
                    xqB[p].x = *(const float*)(xpB + voffs[2 * p]);
                    xqB[p].y = *(const float*)(xpB + voffs[2 * p + 1]);
                }
            }
            #pragma unroll
            for (int u = 0; u < 8; ++u) voffs[u] = (voffs[u] + vd8) & vmask;
            #pragma unroll
            for (int p = 0; p < 4; ++p) {
                float2 xA = (blk & 1) ? xqA[p] : xaA[p];
                float2 xB = (blk & 1) ? xqB[p] : xaB[p];
                const int s0 = blk * 8 + 2 * p;
                // interleave the two independent streams (fills chain stalls)
                STEP(cA, hnA, o_ptrA, pkfma_init<0>(xA, wih_if, b_if),
                     pkfma_init<0>(xA, wih_go, b_go), s0);
                STEP(cB, hnB, o_ptrB, pkfma_init<0>(xB, wih_if, b_if),
                     pkfma_init<0>(xB, wih_go, b_go), s0);
                STEP(cA, hnA, o_ptrA, pkfma_init<1>(xA, wih_if, b_if),
                     pkfma_init<1>(xA, wih_go, b_go), s0 + 1);
                STEP(cB, hnB, o_ptrB, pkfma_init<1>(xB, wih_if, b_if),
                     pkfma_init<1>(xB, wih_go, b_go), s0 + 1);
            }
        }
        // coalesced flush of 32 outputs per elem per stream
        __builtin_amdgcn_wave_barrier();
        {
            const int le = lane >> 4, lo = lane & 15;
            const int bb = blockIdx.x * 16 + wv * 4 + le;
            float a0 = o_baseA[(le * 2 + 0) * 72 + lo]      + o_baseA[(le * 2 + 1) * 72 + lo];
            float a1 = o_baseA[(le * 2 + 0) * 72 + lo + 16] + o_baseA[(le * 2 + 1) * 72 + lo + 16];
            float q0 = o_baseB[(le * 2 + 0) * 72 + lo]      + o_baseB[(le * 2 + 1) * 72 + lo];
            float q1 = o_baseB[(le * 2 + 0) * 72 + lo + 16] + o_baseB[(le * 2 + 1) * 72 + lo + 16];
            out[bb * SLEN + T + lo]               = a0 + bout;
            out[bb * SLEN + T + 16 + lo]          = a1 + bout;
            out[(bb + HBAT) * SLEN + T + lo]      = q0 + bout;
            out[(bb + HBAT) * SLEN + T + 16 + lo] = q1 + bout;
        }
        __builtin_amdgcn_wave_barrier();
    }
}

extern "C" void kernel_launch(void* const* d_in, const int* in_sizes, int n_in,
                              void* d_out, int out_size, void* d_ws, size_t ws_size,
                              hipStream_t stream) {
    const float* xp     = (const float*)d_in[0];
    const float* wihf   = (const float*)d_in[1];
    const float* whhf   = (const float*)d_in[2];
    const float* bihf   = (const float*)d_in[3];
    const float* bhhf   = (const float*)d_in[4];
    const float* wihb   = (const float*)d_in[5];
    const float* whhb   = (const float*)d_in[6];
    const float* bihb   = (const float*)d_in[7];
    const float* bhhb   = (const float*)d_in[8];
    const float* wo     = (const float*)d_in[9];
    const float* bo     = (const float*)d_in[10];
    const int*   futp   = (const int*)d_in[11];
    float*       outp   = (float*)d_out;

    dim3 grid(HBAT / 16);   // 128 blocks: each lane carries 2 batch elems
    dim3 block(256);
    hipLaunchKernelGGL(bilstm_kernel, grid, block, 0, stream,
                       xp, wihf, whhf, bihf, bhhf, wihb, whhb, bihb, bhhb,
                       wo, bo, futp, outp);
}

// Round 13
// 293.662 us; speedup vs baseline: 1.8267x; 1.8267x over previous
//
#include <hip/hip_runtime.h>

#define SLEN  2048
#define BATCH 4096

// DPP cross-lane move (VALU-speed, no LDS/lgkm).
template<int CTRL>
__device__ __forceinline__ float dppf(float v) {
    return __int_as_float(
        __builtin_amdgcn_update_dpp(0, __float_as_int(v), CTRL, 0xF, 0xF, true));
}
#define DPP_XOR1 0xB1   // quad_perm [1,0,3,2]
#define DPP_XOR2 0x4E   // quad_perm [2,3,0,1]
#define DPP_XOR3 0x1B   // quad_perm [3,2,1,0]
#define DPP_XOR7 0x141  // ROW_HALF_MIRROR (i ^ 7 within 8)

// dst = bcast(x2[Q]) * w + b   (op_sel dword-broadcast from a pair; fresh dest)
template<int Q>
__device__ __forceinline__ float2 pkfma_init(float2 x2, float2 w, float2 b) {
    float2 dst;
    if constexpr (Q == 0)
        asm("v_pk_fma_f32 %0, %1, %2, %3 op_sel:[0,0,0] op_sel_hi:[0,1,1]"
            : "=v"(dst) : "v"(x2), "v"(w), "v"(b));
    else
        asm("v_pk_fma_f32 %0, %1, %2, %3 op_sel:[1,0,0] op_sel_hi:[1,1,1]"
            : "=v"(dst) : "v"(x2), "v"(w), "v"(b));
    return dst;
}
// acc += bcast(h2[Q]) * w  (op_sel dword-broadcast; tied accumulator)
template<int Q>
__device__ __forceinline__ void pkfma_bc(float2& acc, float2 h2, float2 w) {
    if constexpr (Q == 0)
        asm("v_pk_fma_f32 %0, %1, %2, %0 op_sel:[0,0,0] op_sel_hi:[0,1,1]"
            : "+v"(acc) : "v"(h2), "v"(w));
    else
        asm("v_pk_fma_f32 %0, %1, %2, %0 op_sel:[1,0,0] op_sel_hi:[1,1,1]"
            : "+v"(acc) : "v"(h2), "v"(w));
}

extern "C" __global__ __launch_bounds__(256, 1)
void bilstm_kernel(const float* __restrict__ x,
                   const float* __restrict__ w_ih_f, const float* __restrict__ w_hh_f,
                   const float* __restrict__ b_ih_f, const float* __restrict__ b_hh_f,
                   const float* __restrict__ w_ih_b, const float* __restrict__ w_hh_b,
                   const float* __restrict__ b_ih_b, const float* __restrict__ b_hh_b,
                   const float* __restrict__ w_out, const float* __restrict__ b_out,
                   const int* __restrict__ future_p,
                   float* __restrict__ out)
{
    const int tid  = threadIdx.x;
    const int wv   = tid >> 6;     // wave in block (0..3)
    const int lane = tid & 63;
    const int e    = lane >> 4;    // batch elem within wave (0..3)
    const int r    = lane & 15;
    const int d    = r >> 3;       // 0 = fwd, 1 = bwd
    const int j    = r & 7;        // hidden index
    const int b    = blockIdx.x * 16 + wv * 4 + e;

    const float* wih_p = d ? w_ih_b : w_ih_f;
    const float* whh_p = d ? w_hh_b : w_hh_f;
    const float* bih_p = d ? b_ih_b : b_ih_f;
    const float* bhh_p = d ? b_hh_b : b_hh_f;

    // Prescale so gate accumulators emerge as exp2 arguments:
    //   sigmoid(v) = 1/(1+exp2(-log2e*v)),  tanh(v) = (1-E)/(1+E), E=exp2(-2log2e*v)
    const float SI  = -1.4426950408889634f;   // i, f, o rows
    const float SG  = -2.8853900817779268f;   // g row
    const float nSG =  2.8853900817779268f;

    // Butterfly slot -> h index xor mask (pairs: lo,hi of P0..P3)
    const int M[8] = {0, 1, 2, 3, 7, 6, 5, 4};
    float2 Wif[8], Wgo[8], wih_if, wih_go, b_if, b_go;
    #pragma unroll
    for (int m = 0; m < 8; ++m) {
        const int idx = j ^ M[m];
        Wif[m].x = SI * whh_p[(0 + j) * 8 + idx];     // gate i
        Wif[m].y = SI * whh_p[(8 + j) * 8 + idx];     // gate f
        Wgo[m].x = SG * whh_p[(16 + j) * 8 + idx];    // gate g
        Wgo[m].y = SI * whh_p[(24 + j) * 8 + idx];    // gate o
    }
    wih_if.x = SI * wih_p[0 + j];   wih_if.y = SI * wih_p[8 + j];
    wih_go.x = SG * wih_p[16 + j];  wih_go.y = SI * wih_p[24 + j];
    b_if.x = SI * (bih_p[0 + j]  + bhh_p[0 + j]);
    b_if.y = SI * (bih_p[8 + j]  + bhh_p[8 + j]);
    b_go.x = SG * (bih_p[16 + j] + bhh_p[16 + j]);
    b_go.y = SI * (bih_p[24 + j] + bhh_p[24 + j]);

    const float wout = w_out[d * 8 + j];
    const float bout = b_out[0];
    const int   fut  = future_p[0];

    // [wave][row = e*2+d][72]: slots 0..31 = outputs (written by j==0 lane),
    // slots 32+j+slot = dump region for the non-writer lanes (never read).
    __shared__ float o_lds[4][8][72];
    float* o_ptr = &o_lds[wv][e * 2 + d][(j == 0) ? 0 : (32 + j)];
    float* o_base = &o_lds[wv][0][0];

    float cS = 0.0f;   // scaled cell state: cS = SG * c
    float hn = 0.0f;

    // x addressing: byte-voffsets walk rows; x spans 2^25 bytes so the bwd
    // mod-S wrap is a simple mask (batch offset lives in the low 14 bits).
    const char* xb = (const char*)x;
    const unsigned vdelta  = d ? (unsigned)(-(BATCH * 4)) : (unsigned)(BATCH * 4);
    const unsigned vd8     = vdelta * 8u;
    const unsigned vmask   = (unsigned)(SLEN * BATCH * 4 - 1);
    unsigned voffs[8];
    {
        unsigned v0 = ((unsigned)(d ? (fut & (SLEN - 1)) : 0) * BATCH + (unsigned)b) * 4u;
        #pragma unroll
        for (int u = 0; u < 8; ++u) { voffs[u] = v0; v0 = (v0 + vdelta) & vmask; }
    }

    // x pairs: xa2[p] holds steps (2p, 2p+1) of the current 8-step block
    float2 xa2[4], xb2[4];
    #pragma unroll
    for (int p = 0; p < 4; ++p) {
        xa2[p].x = *(const float*)(xb + voffs[2 * p]);
        xa2[p].y = *(const float*)(xb + voffs[2 * p + 1]);
    }
    #pragma unroll
    for (int u = 0; u < 8; ++u) voffs[u] = (voffs[u] + vd8) & vmask;

    // acc_if/acc_go arrive pre-initialized with x*w_ih + bias
    auto STEP = [&](float2 acc_if, float2 acc_go, int slot) {
        // all-gather h across the 8 j-lanes of this (e,d): 7 DPP movs
        float2 P0, P1, P2, P3;
        P0.x = hn;                      // h[j]
        P0.y = dppf<DPP_XOR1>(hn);      // h[j^1]
        P1.x = dppf<DPP_XOR2>(hn);      // h[j^2]
        P1.y = dppf<DPP_XOR3>(hn);      // h[j^3]
        P2.x = dppf<DPP_XOR7>(P0.x);    // h[j^7]
        P2.y = dppf<DPP_XOR7>(P0.y);    // h[j^6]
        P3.x = dppf<DPP_XOR7>(P1.x);    // h[j^5]
        P3.y = dppf<DPP_XOR7>(P1.y);    // h[j^4]

        pkfma_bc<0>(acc_if, P0, Wif[0]);  pkfma_bc<1>(acc_if, P0, Wif[1]);
        pkfma_bc<0>(acc_if, P1, Wif[2]);  pkfma_bc<1>(acc_if, P1, Wif[3]);
        pkfma_bc<0>(acc_if, P2, Wif[4]);  pkfma_bc<1>(acc_if, P2, Wif[5]);
        pkfma_bc<0>(acc_if, P3, Wif[6]);  pkfma_bc<1>(acc_if, P3, Wif[7]);
        pkfma_bc<0>(acc_go, P0, Wgo[0]);  pkfma_bc<1>(acc_go, P0, Wgo[1]);
        pkfma_bc<0>(acc_go, P1, Wgo[2]);  pkfma_bc<1>(acc_go, P1, Wgo[3]);
        pkfma_bc<0>(acc_go, P2, Wgo[4]);  pkfma_bc<1>(acc_go, P2, Wgo[5]);
        pkfma_bc<0>(acc_go, P3, Wgo[6]);  pkfma_bc<1>(acc_go, P3, Wgo[7]);

        // activations: 5 exp2 + 2 rcp (single gate-side rcp, plain-mul recovery)
        float ei = __builtin_amdgcn_exp2f(acc_if.x);
        float ef = __builtin_amdgcn_exp2f(acc_if.y);
        float eg = __builtin_amdgcn_exp2f(acc_go.x);
        float eo = __builtin_amdgcn_exp2f(acc_go.y);
        float ei1 = 1.0f + ei, ef1 = 1.0f + ef, eg1 = 1.0f + eg, eo1 = 1.0f + eo;
        float m1 = ei1 * eg1;
        float m2 = ef1 * eo1;
        float rP = __builtin_amdgcn_rcpf(m1 * m2);
        float riu = rP * m2;                 // 1/(ei1*eg1)
        float t3  = rP * m1;                 // 1/(ef1*eo1)
        float tg  = fmaf(eg, nSG, SG);       // SG*(1-eg)
        float igS = tg * riu;                // SG * ia*ga
        float fa  = t3 * eo1;                // sigmoid(f)
        float oa  = t3 * ef1;                // sigmoid(o)
        cS = fmaf(fa, cS, igS);              // cS = SG*c
        float tc  = __builtin_amdgcn_exp2f(cS);
        float rt  = __builtin_amdgcn_rcpf(1.0f + tc);
        float oa2 = oa + oa;
        hn = fmaf(oa2, rt, -oa);             // oa * tanh(c)

        // per-(e,d) output partial: reduce over the 8 j-lanes, dump-write
        float p = hn * wout;
        p += dppf<DPP_XOR1>(p);
        p += dppf<DPP_XOR2>(p);
        p += dppf<DPP_XOR7>(p);
        o_ptr[slot] = p;
    };

    for (int T = 0; T < SLEN; T += 32) {
        #pragma unroll
        for (int blk = 0; blk < 4; ++blk) {
            // prefetch next 8 x values into the other bank
            #pragma unroll
            for (int p = 0; p < 4; ++p) {
                if (blk & 1) {
                    xa2[p].x = *(const float*)(xb + voffs[2 * p]);
                    xa2[p].y = *(const float*)(xb + voffs[2 * p + 1]);
                } else {
                    xb2[p].x = *(const float*)(xb + voffs[2 * p]);
                    xb2[p].y = *(const float*)(xb + voffs[2 * p + 1]);
                }
            }
            #pragma unroll
            for (int u = 0; u < 8; ++u) voffs[u] = (voffs[u] + vd8) & vmask;
            #pragma unroll
            for (int p = 0; p < 4; ++p) {
                float2 x2 = (blk & 1) ? xb2[p] : xa2[p];
                STEP(pkfma_init<0>(x2, wih_if, b_if),
                     pkfma_init<0>(x2, wih_go, b_go), blk * 8 + 2 * p);
                STEP(pkfma_init<1>(x2, wih_if, b_if),
                     pkfma_init<1>(x2, wih_go, b_go), blk * 8 + 2 * p + 1);
            }
        }
        // coalesced flush of 32 outputs per elem (sum dir partials here)
        __builtin_amdgcn_wave_barrier();
        {
            const int le = lane >> 4, lo = lane & 15;
            const int bb = blockIdx.x * 16 + wv * 4 + le;
            float v0 = o_base[(le * 2 + 0) * 72 + lo]      + o_base[(le * 2 + 1) * 72 + lo];
            float v1 = o_base[(le * 2 + 0) * 72 + lo + 16] + o_base[(le * 2 + 1) * 72 + lo + 16];
            out[bb * SLEN + T + lo]      = v0 + bout;
            out[bb * SLEN + T + 16 + lo] = v1 + bout;
        }
        __builtin_amdgcn_wave_barrier();
    }
}

extern "C" void kernel_launch(void* const* d_in, const int* in_sizes, int n_in,
                              void* d_out, int out_size, void* d_ws, size_t ws_size,
                              hipStream_t stream) {
    const float* xp     = (const float*)d_in[0];
    const float* wihf   = (const float*)d_in[1];
    const float* whhf   = (const float*)d_in[2];
    const float* bihf   = (const float*)d_in[3];
    const float* bhhf   = (const float*)d_in[4];
    const float* wihb   = (const float*)d_in[5];
    const float* whhb   = (const float*)d_in[6];
    const float* bihb   = (const float*)d_in[7];
    const float* bhhb   = (const float*)d_in[8];
    const float* wo     = (const float*)d_in[9];
    const float* bo     = (const float*)d_in[10];
    const int*   futp   = (const int*)d_in[11];
    float*       outp   = (float*)d_out;

    dim3 grid(BATCH / 16);
    dim3 block(256);
    hipLaunchKernelGGL(bilstm_kernel, grid, block, 0, stream,
                       xp, wihf, whhf, bihf, bhhf, wihb, whhb, bihb, bhhb,
                       wo, bo, futp, outp);
}